// Round 3
// baseline (282.012 us; speedup 1.0000x reference)
//
#include <hip/hip_runtime.h>
#include <hip/hip_bf16.h>
#include <stdint.h>

typedef unsigned short u16;
typedef __bf16 v8bf __attribute__((ext_vector_type(8)));
typedef float  v4f  __attribute__((ext_vector_type(4)));

#define N_ROWS 8192
#define C_REAL 10000
#define C_PAD  10240   /* 40 * 256 */
#define D_DIM  512
#define BM 256
#define BN 256
#define BK 64
#define KTILES (D_DIM / BK)   /* 8 */
#define OTILES 5              /* col-tiles per block: 40 / 8 XCDs */

/* LDS map (bytes): buf0 @0, buf1 @65536; within a buf:
   A-half0 @0, A-half1 @16384, B-half0 @32768, B-half1 @49152.
   f2s @131072 (1KB), c2s @132096 (2KB, double-buffered), labs @134144 (1KB). */
#define SM_BUF   65536
#define SM_HALF  16384
#define SM_BOFF  32768
#define SM_F2   131072
#define SM_C2   132096
#define SM_LAB  134144
#define SM_TOTAL 135168
static_assert(SM_TOTAL <= 160 * 1024, "LDS budget");

#define BARRIER() do { asm volatile("" ::: "memory"); \
                       __builtin_amdgcn_s_barrier();  \
                       asm volatile("" ::: "memory"); } while (0)
#define MFMA(d, a, b) d = __builtin_amdgcn_mfma_f32_16x16x32_bf16(a, b, d, 0, 0, 0)
#define GLL(gp, lp) __builtin_amdgcn_global_load_lds( \
    (const __attribute__((address_space(1))) void*)(gp), \
    (__attribute__((address_space(3))) void*)(lp), 16, 0, 0)

__device__ __forceinline__ unsigned pack2bf(float a, float b) {
    unsigned short ua = __builtin_bit_cast(unsigned short, (__bf16)a);
    unsigned short ub = __builtin_bit_cast(unsigned short, (__bf16)b);
    return (unsigned)ua | ((unsigned)ub << 16);
}

// One wave per row: L2-normalize, write bf16 row + f32 sum-of-squares-of-normalized.
// Rows >= nreal are padding: bf16 zeros, o2 = 1e30 (=> dis = -5e30 => exp = 0).
__global__ __launch_bounds__(256) void norm_rows_kernel(
    const float* __restrict__ x, u16* __restrict__ ob, float* __restrict__ o2,
    int nreal, int ntotal)
{
    int row  = blockIdx.x * 4 + (threadIdx.x >> 6);
    int lane = threadIdx.x & 63;
    if (row >= ntotal) return;
    uint2* orow = (uint2*)(ob + (size_t)row * D_DIM);
    if (row >= nreal) {
        uint2 z; z.x = 0u; z.y = 0u;
        orow[lane] = z; orow[64 + lane] = z;
        if (lane == 0) o2[row] = 1e30f;
        return;
    }
    const float4* xr = (const float4*)(x + (size_t)row * D_DIM);
    float4 v0 = xr[lane];
    float4 v1 = xr[64 + lane];
    float s = v0.x*v0.x + v0.y*v0.y + v0.z*v0.z + v0.w*v0.w
            + v1.x*v1.x + v1.y*v1.y + v1.z*v1.z + v1.w*v1.w;
    #pragma unroll
    for (int m = 1; m < 64; m <<= 1) s += __shfl_xor(s, m, 64);
    float nrm = sqrtf(s);
    float inv = 1.0f / fmaxf(nrm, 1e-12f);
    if (lane == 0) o2[row] = s * inv * inv;
    uint2 p0, p1;
    p0.x = pack2bf(v0.x * inv, v0.y * inv);
    p0.y = pack2bf(v0.z * inv, v0.w * inv);
    p1.x = pack2bf(v1.x * inv, v1.y * inv);
    p1.y = pack2bf(v1.z * inv, v1.w * inv);
    orow[lane]      = p0;
    orow[64 + lane] = p1;
}

// Exact (f32) positive-class distance: one wave per row, gathered center row.
__global__ __launch_bounds__(256) void pos_exact_kernel(
    const float* __restrict__ feat, const float* __restrict__ cent,
    const int* __restrict__ labels, float* __restrict__ pose)
{
    int row  = blockIdx.x * 4 + (threadIdx.x >> 6);
    int lane = threadIdx.x & 63;
    int lab  = labels[row];
    const float4* fr = (const float4*)(feat + (size_t)row * D_DIM);
    const float4* cr = (const float4*)(cent + (size_t)lab * D_DIM);
    float sf = 0.f, sc = 0.f, sd = 0.f;
    #pragma unroll
    for (int i = 0; i < 2; ++i) {
        float4 a = fr[i * 64 + lane];
        float4 b = cr[i * 64 + lane];
        sf += a.x*a.x + a.y*a.y + a.z*a.z + a.w*a.w;
        sc += b.x*b.x + b.y*b.y + b.z*b.z + b.w*b.w;
        sd += a.x*b.x + a.y*b.y + a.z*b.z + a.w*b.w;
    }
    #pragma unroll
    for (int m = 1; m < 64; m <<= 1) {
        sf += __shfl_xor(sf, m, 64);
        sc += __shfl_xor(sc, m, 64);
        sd += __shfl_xor(sd, m, 64);
    }
    if (lane == 0) {
        float nf = fmaxf(sqrtf(sf), 1e-12f);
        float nc = fmaxf(sqrtf(sc), 1e-12f);
        float invf = 1.f / nf, invc = 1.f / nc;
        float f2n = sf * invf * invf;
        float c2n = sc * invc * invc;
        float dtn = sd * invf * invc;
        pose[row] = -5.0f * (f2n + c2n - 2.0f * dtn);
    }
}

// Persistent 256-block GEMM: each block = one 256-row tile x 5 col-tiles
// (XCD-partitioned), 8-wave 4-phase pipelined K-loop, fused exp epilogue.
__global__ __launch_bounds__(512, 2) void gemm_kernel(
    const u16* __restrict__ A, const u16* __restrict__ B,
    const float* __restrict__ f2, const float* __restrict__ c2,
    const int* __restrict__ labels,
    float* __restrict__ rowsum, float* __restrict__ posdis)
{
    extern __shared__ char sm[];
    const int xcd = blockIdx.x & 7;
    const int rt  = blockIdx.x >> 3;
    const int rowBase = rt * BM;
    const int tid  = threadIdx.x;
    const int lane = tid & 63;
    const int w    = tid >> 6;
    const int wr   = w >> 2;        // 0..1 : 128-row group
    const int wc   = w & 3;         // 0..3 : 64-col group
    const int l15  = lane & 15;
    const int h4   = lane >> 4;
    const int xorv = l15 & 7;
    const int bRow0 = (wc & 1) * 64;

    // ---- precomputed per-thread offsets ----
    // staging: thread covers chunk tid (rows 0-63 of a half) and tid+512 (rows 64-127)
    const int r0  = tid >> 3;
    const int lc0 = (tid & 7) ^ (r0 & 7);
    const size_t tOff = (size_t)r0 * D_DIM + lc0 * 8;   // elements; +64*D_DIM for upper
    const int ldst = tid * 16;                           // LDS byte slot (i=0); +8192 for i=1

    // ds_read offsets (bytes, relative to buffer base)
    int aO[4][2], bO[4][2];
    #pragma unroll
    for (int m = 0; m < 4; ++m)
        #pragma unroll
        for (int ks = 0; ks < 2; ++ks)
            aO[m][ks] = wr * SM_HALF + (m * 16 + l15) * 128
                      + (((((ks << 2) + h4)) ^ xorv) << 4);
    #pragma unroll
    for (int n = 0; n < 4; ++n)
        #pragma unroll
        for (int ks = 0; ks < 2; ++ks)
            bO[n][ks] = SM_BOFF + (wc >> 1) * SM_HALF + (bRow0 + n * 16 + l15) * 128
                      + (((((ks << 2) + h4)) ^ xorv) << 4);

    const u16* Arow = A + (size_t)rowBase * D_DIM;   // A rows fixed for the block

    auto stage_tile = [&](int colB, int kt, char* dst) {
        const u16* Ab = Arow + kt * BK;
        const u16* Bb = B + (size_t)colB * D_DIM + kt * BK;
        GLL(Ab + tOff,                           dst + ldst);
        GLL(Ab + tOff + (size_t)64  * D_DIM,     dst + 8192 + ldst);
        GLL(Ab + tOff + (size_t)128 * D_DIM,     dst + SM_HALF + ldst);
        GLL(Ab + tOff + (size_t)192 * D_DIM,     dst + SM_HALF + 8192 + ldst);
        GLL(Bb + tOff,                           dst + SM_BOFF + ldst);
        GLL(Bb + tOff + (size_t)64  * D_DIM,     dst + SM_BOFF + 8192 + ldst);
        GLL(Bb + tOff + (size_t)128 * D_DIM,     dst + SM_BOFF + SM_HALF + ldst);
        GLL(Bb + tOff + (size_t)192 * D_DIM,     dst + SM_BOFF + SM_HALF + 8192 + ldst);
    };
    auto stage_c2 = [&](int colB, int par) {
        if (tid < 64) GLL(c2 + colB + tid * 4, sm + SM_C2 + par * 1024 + tid * 16);
    };

    // ---- prologue ----
    const int colB0 = (xcd * OTILES) * BN;
    if (tid < 256) {
        ((float*)(sm + SM_F2))[tid] = f2[rowBase + tid];
        ((int*)(sm + SM_LAB))[tid]  = labels[rowBase + tid];
    } else {
        ((float*)(sm + SM_C2))[tid - 256] = c2[colB0 + (tid - 256)];
    }
    stage_tile(colB0, 0, sm);
    __syncthreads();

    v4f acc[8][4];
    #pragma unroll
    for (int m = 0; m < 8; ++m)
        #pragma unroll
        for (int n = 0; n < 4; ++n) acc[m][n] = (v4f){0.f, 0.f, 0.f, 0.f};

    v8bf aF[4][2], bFa[2][2], bFb[2][2];

    auto epilogue = [&](int colBase, int par) {
        const float* f2s  = (const float*)(sm + SM_F2);
        const float* c2s  = (const float*)(sm + SM_C2 + par * 1024);
        const int*   labs = (const int*)(sm + SM_LAB);
        #pragma unroll
        for (int m = 0; m < 8; ++m) {
            float s[4] = {0.f, 0.f, 0.f, 0.f};
            const int lr0 = wr * 128 + m * 16 + h4 * 4;
            #pragma unroll
            for (int n = 0; n < 4; ++n) {
                const int lcol = wc * 64 + n * 16 + l15;
                const int gcol = colBase + lcol;
                const float cc = c2s[lcol];
                #pragma unroll
                for (int j = 0; j < 4; ++j) {
                    const int lr = lr0 + j;
                    float dis = -5.0f * (f2s[lr] + cc - 2.0f * acc[m][n][j]);
                    float e = __expf(dis);
                    s[j] += e;
                    if (labs[lr] == gcol) posdis[rowBase + lr] = dis;
                }
            }
            #pragma unroll
            for (int msk = 1; msk < 16; msk <<= 1) {
                #pragma unroll
                for (int j = 0; j < 4; ++j) s[j] += __shfl_xor(s[j], msk, 64);
            }
            if (l15 == 0) {
                #pragma unroll
                for (int j = 0; j < 4; ++j)
                    atomicAdd(&rowsum[rowBase + lr0 + j], s[j]);
            }
        }
    };

    #pragma unroll 1
    for (int c = 0; c < OTILES; ++c) {
        const int colB = (xcd * OTILES + c) * BN;
        #pragma unroll 2
        for (int kt = 0; kt < KTILES; ++kt) {
            const int v = c * KTILES + kt;
            const char* smc = sm + (v & 1) * SM_BUF;
            char*      bufn = sm + ((v + 1) & 1) * SM_BUF;

            // ---- phase 0: read aF(lo) + bFa; stage next tile ----
            #pragma unroll
            for (int m = 0; m < 4; ++m)
                #pragma unroll
                for (int ks = 0; ks < 2; ++ks)
                    aF[m][ks] = *(const v8bf*)(smc + aO[m][ks]);
            #pragma unroll
            for (int n = 0; n < 2; ++n)
                #pragma unroll
                for (int ks = 0; ks < 2; ++ks)
                    bFa[n][ks] = *(const v8bf*)(smc + bO[n][ks]);
            if (kt < KTILES - 1) {
                stage_tile(colB, kt + 1, bufn);
            } else if (c < OTILES - 1) {
                stage_tile(colB + BN, 0, bufn);
                stage_c2(colB + BN, (c + 1) & 1);
            }
            BARRIER();
            __builtin_amdgcn_s_setprio(1);
            #pragma unroll
            for (int m = 0; m < 4; ++m)
                #pragma unroll
                for (int n = 0; n < 2; ++n) {
                    MFMA(acc[m][n], aF[m][0], bFa[n][0]);
                    MFMA(acc[m][n], aF[m][1], bFa[n][1]);
                }
            __builtin_amdgcn_s_setprio(0);
            BARRIER();

            // ---- phase 1: read bFb; MFMA lo x n2,3 ----
            #pragma unroll
            for (int n = 0; n < 2; ++n)
                #pragma unroll
                for (int ks = 0; ks < 2; ++ks)
                    bFb[n][ks] = *(const v8bf*)(smc + bO[n + 2][ks]);
            BARRIER();
            __builtin_amdgcn_s_setprio(1);
            #pragma unroll
            for (int m = 0; m < 4; ++m)
                #pragma unroll
                for (int n = 0; n < 2; ++n) {
                    MFMA(acc[m][n + 2], aF[m][0], bFb[n][0]);
                    MFMA(acc[m][n + 2], aF[m][1], bFb[n][1]);
                }
            __builtin_amdgcn_s_setprio(0);
            BARRIER();

            // ---- phase 2: read aF(hi, +8192); MFMA hi x n2,3 ----
            #pragma unroll
            for (int m = 0; m < 4; ++m)
                #pragma unroll
                for (int ks = 0; ks < 2; ++ks)
                    aF[m][ks] = *(const v8bf*)(smc + aO[m][ks] + 8192);
            BARRIER();
            __builtin_amdgcn_s_setprio(1);
            #pragma unroll
            for (int m = 0; m < 4; ++m)
                #pragma unroll
                for (int n = 0; n < 2; ++n) {
                    MFMA(acc[m + 4][n + 2], aF[m][0], bFb[n][0]);
                    MFMA(acc[m + 4][n + 2], aF[m][1], bFb[n][1]);
                }
            __builtin_amdgcn_s_setprio(0);
            BARRIER();

            // ---- phase 3: MFMA hi x n0,1; drain+barrier unless otile boundary ----
            __builtin_amdgcn_s_setprio(1);
            #pragma unroll
            for (int m = 0; m < 4; ++m)
                #pragma unroll
                for (int n = 0; n < 2; ++n) {
                    MFMA(acc[m + 4][n], aF[m][0], bFa[n][0]);
                    MFMA(acc[m + 4][n], aF[m][1], bFa[n][1]);
                }
            __builtin_amdgcn_s_setprio(0);
            if (kt < KTILES - 1) {
                asm volatile("s_waitcnt vmcnt(0)" ::: "memory");
                BARRIER();
            }
        }

        // otile epilogue (staging for next otile is still in flight underneath)
        epilogue(colB, c & 1);
        #pragma unroll
        for (int m = 0; m < 8; ++m)
            #pragma unroll
            for (int n = 0; n < 4; ++n) acc[m][n] = (v4f){0.f, 0.f, 0.f, 0.f};
        if (c < OTILES - 1) {
            asm volatile("s_waitcnt vmcnt(0)" ::: "memory");
            BARRIER();
        }
    }
}

// Final scalar reduction: loss and unbiased variance (f64 accumulation).
__global__ __launch_bounds__(256) void finalize_kernel(
    const float* __restrict__ posdis, const float* __restrict__ pose,
    const float* __restrict__ rowsum, const int* __restrict__ labels,
    const float* __restrict__ bias, float* __restrict__ out)
{
    int t = threadIdx.x;
    double sl = 0.0, sp = 0.0, sp2 = 0.0;
    for (int r = t; r < N_ROWS; r += 256) {
        float pd = posdis[r];                 // bf16-path label term (matches rowsum)
        float p  = pose[r] + bias[labels[r]]; // exact-path pos_metric
        float num = __expf(p);
        float den = rowsum[r] - __expf(pd) + num;
        sl  += (double)(logf(den) - p);
        sp  += (double)p;
        sp2 += (double)p * (double)p;
    }
    #pragma unroll
    for (int m = 1; m < 64; m <<= 1) {
        sl  += __shfl_xor(sl,  m, 64);
        sp  += __shfl_xor(sp,  m, 64);
        sp2 += __shfl_xor(sp2, m, 64);
    }
    __shared__ double sh[3][4];
    int w = t >> 6, lane = t & 63;
    if (lane == 0) { sh[0][w] = sl; sh[1][w] = sp; sh[2][w] = sp2; }
    __syncthreads();
    if (t == 0) {
        sl  = sh[0][0] + sh[0][1] + sh[0][2] + sh[0][3];
        sp  = sh[1][0] + sh[1][1] + sh[1][2] + sh[1][3];
        sp2 = sh[2][0] + sh[2][1] + sh[2][2] + sh[2][3];
        const double N = (double)N_ROWS;
        double mean = sp / N;
        double var  = (sp2 - N * mean * mean) / (N - 1.0);
        double loss = sl / N + var;
        out[0] = (float)loss;
        out[1] = (float)var;
    }
}

extern "C" void kernel_launch(void* const* d_in, const int* in_sizes, int n_in,
                              void* d_out, int out_size, void* d_ws, size_t ws_size,
                              hipStream_t stream) {
    const float* features = (const float*)d_in[0];
    const int*   labels   = (const int*)d_in[1];
    const float* centers  = (const float*)d_in[2];
    const float* bias     = (const float*)d_in[3];
    float* out = (float*)d_out;
    char* ws = (char*)d_ws;

    // Workspace layout (16B aligned), ~19.1 MB total.
    u16*   fb     = (u16*)(ws);                 // 8192*512*2  = 8388608
    u16*   cb     = (u16*)(ws + 8388608);       // 10240*512*2 = 10485760
    float* f2     = (float*)(ws + 18874368);    // 8192*4
    float* c2     = (float*)(ws + 18907136);    // 10240*4
    float* rowsum = (float*)(ws + 18948096);    // 8192*4
    float* posdis = (float*)(ws + 18980864);    // 8192*4
    float* pose   = (float*)(ws + 19013632);    // 8192*4

    hipMemsetAsync(rowsum, 0, N_ROWS * sizeof(float), stream);

    hipLaunchKernelGGL(norm_rows_kernel, dim3(N_ROWS / 4), dim3(256), 0, stream,
                       features, fb, f2, N_ROWS, N_ROWS);
    hipLaunchKernelGGL(norm_rows_kernel, dim3(C_PAD / 4), dim3(256), 0, stream,
                       centers, cb, c2, C_REAL, C_PAD);
    hipLaunchKernelGGL(pos_exact_kernel, dim3(N_ROWS / 4), dim3(256), 0, stream,
                       features, centers, labels, pose);

    hipFuncSetAttribute(reinterpret_cast<const void*>(gemm_kernel),
                        hipFuncAttributeMaxDynamicSharedMemorySize, SM_TOTAL);
    hipLaunchKernelGGL(gemm_kernel, dim3(256), dim3(512), SM_TOTAL, stream,
                       fb, cb, f2, c2, labels, rowsum, posdis);

    hipLaunchKernelGGL(finalize_kernel, dim3(1), dim3(256), 0, stream,
                       posdis, pose, rowsum, labels, bias, out);
}

// Round 4
// 271.081 us; speedup vs baseline: 1.0403x; 1.0403x over previous
//
#include <hip/hip_runtime.h>
#include <hip/hip_bf16.h>
#include <stdint.h>

typedef unsigned short u16;
typedef __bf16 v8bf __attribute__((ext_vector_type(8)));
typedef float  v4f  __attribute__((ext_vector_type(4)));

#define N_ROWS 8192
#define C_REAL 10000
#define C_PAD  10240   /* 40 * 256 */
#define D_DIM  512
#define BM 256
#define BN 256
#define BK 64
#define KTILES (D_DIM / BK)   /* 8 */

/* LDS map (bytes): buf0 @0, buf1 @65536; within a buf:
   A-half0 @0, A-half1 @16384, B-half0 @32768, B-half1 @49152.
   f2s @131072, c2s @132096, labs @133120. */
#define SM_BUF   65536
#define SM_HALF  16384
#define SM_BOFF  32768
#define SM_F2   131072
#define SM_C2   132096
#define SM_LAB  133120
#define SM_TOTAL 134144
static_assert(SM_TOTAL <= 160 * 1024, "LDS budget");

#define BARRIER() do { asm volatile("" ::: "memory"); \
                       __builtin_amdgcn_s_barrier();  \
                       asm volatile("" ::: "memory"); } while (0)
#define MFMA(d, a, b) d = __builtin_amdgcn_mfma_f32_16x16x32_bf16(a, b, d, 0, 0, 0)
#define GLL(gp, lp) __builtin_amdgcn_global_load_lds( \
    (const __attribute__((address_space(1))) void*)(gp), \
    (__attribute__((address_space(3))) void*)(lp), 16, 0, 0)

__device__ __forceinline__ unsigned pack2bf(float a, float b) {
    unsigned short ua = __builtin_bit_cast(unsigned short, (__bf16)a);
    unsigned short ub = __builtin_bit_cast(unsigned short, (__bf16)b);
    return (unsigned)ua | ((unsigned)ub << 16);
}

// One wave per row: L2-normalize, write bf16 row + f32 sum-of-squares-of-normalized.
// Rows >= nreal are padding: bf16 zeros, o2 = 1e30 (=> dis = -5e30 => exp = 0).
__global__ __launch_bounds__(256) void norm_rows_kernel(
    const float* __restrict__ x, u16* __restrict__ ob, float* __restrict__ o2,
    int nreal, int ntotal)
{
    int row  = blockIdx.x * 4 + (threadIdx.x >> 6);
    int lane = threadIdx.x & 63;
    if (row >= ntotal) return;
    uint2* orow = (uint2*)(ob + (size_t)row * D_DIM);
    if (row >= nreal) {
        uint2 z; z.x = 0u; z.y = 0u;
        orow[lane] = z; orow[64 + lane] = z;
        if (lane == 0) o2[row] = 1e30f;
        return;
    }
    const float4* xr = (const float4*)(x + (size_t)row * D_DIM);
    float4 v0 = xr[lane];
    float4 v1 = xr[64 + lane];
    float s = v0.x*v0.x + v0.y*v0.y + v0.z*v0.z + v0.w*v0.w
            + v1.x*v1.x + v1.y*v1.y + v1.z*v1.z + v1.w*v1.w;
    #pragma unroll
    for (int m = 1; m < 64; m <<= 1) s += __shfl_xor(s, m, 64);
    float nrm = sqrtf(s);
    float inv = 1.0f / fmaxf(nrm, 1e-12f);
    if (lane == 0) o2[row] = s * inv * inv;
    uint2 p0, p1;
    p0.x = pack2bf(v0.x * inv, v0.y * inv);
    p0.y = pack2bf(v0.z * inv, v0.w * inv);
    p1.x = pack2bf(v1.x * inv, v1.y * inv);
    p1.y = pack2bf(v1.z * inv, v1.w * inv);
    orow[lane]      = p0;
    orow[64 + lane] = p1;
}

// Exact (f32) positive-class distance: one wave per row, gathered center row.
__global__ __launch_bounds__(256) void pos_exact_kernel(
    const float* __restrict__ feat, const float* __restrict__ cent,
    const int* __restrict__ labels, float* __restrict__ pose)
{
    int row  = blockIdx.x * 4 + (threadIdx.x >> 6);
    int lane = threadIdx.x & 63;
    int lab  = labels[row];
    const float4* fr = (const float4*)(feat + (size_t)row * D_DIM);
    const float4* cr = (const float4*)(cent + (size_t)lab * D_DIM);
    float sf = 0.f, sc = 0.f, sd = 0.f;
    #pragma unroll
    for (int i = 0; i < 2; ++i) {
        float4 a = fr[i * 64 + lane];
        float4 b = cr[i * 64 + lane];
        sf += a.x*a.x + a.y*a.y + a.z*a.z + a.w*a.w;
        sc += b.x*b.x + b.y*b.y + b.z*b.z + b.w*b.w;
        sd += a.x*b.x + a.y*b.y + a.z*b.z + a.w*b.w;
    }
    #pragma unroll
    for (int m = 1; m < 64; m <<= 1) {
        sf += __shfl_xor(sf, m, 64);
        sc += __shfl_xor(sc, m, 64);
        sd += __shfl_xor(sd, m, 64);
    }
    if (lane == 0) {
        float nf = fmaxf(sqrtf(sf), 1e-12f);
        float nc = fmaxf(sqrtf(sc), 1e-12f);
        float invf = 1.f / nf, invc = 1.f / nc;
        float f2n = sf * invf * invf;
        float c2n = sc * invc * invc;
        float dtn = sd * invf * invc;
        pose[row] = -5.0f * (f2n + c2n - 2.0f * dtn);
    }
}

// 256x256x(BK=64) 8-wave MFMA GEMM. Grid (40,32): linear id = x + 40*y,
// 40 % 8 == 0 => XCD = x % 8, so each XCD sees 5 col-tiles (B slice 1.3 MB)
// + ~6 concurrent row-tiles -> everything L2-resident (round-2 measured
// FETCH 38 MB). One barrier + one vmcnt per K-tile; all 24 fragment reads
// issued before the 64 MFMAs so compiler's counted lgkmcnt overlaps LDS
// service with matrix-pipe drain. Fused exp epilogue.
__global__ __launch_bounds__(512, 2) void gemm_kernel(
    const u16* __restrict__ A, const u16* __restrict__ B,
    const float* __restrict__ f2, const float* __restrict__ c2,
    const int* __restrict__ labels,
    float* __restrict__ rowsum, float* __restrict__ posdis)
{
    extern __shared__ char sm[];
    const int rowBase = blockIdx.y * BM;
    const int colBase = blockIdx.x * BN;
    const int tid  = threadIdx.x;
    const int lane = tid & 63;
    const int w    = tid >> 6;
    const int wr   = w >> 2;        // 0..1 : 128-row group
    const int wc   = w & 3;         // 0..3 : 64-col group
    const int l15  = lane & 15;
    const int h4   = lane >> 4;
    const int xorv = l15 & 7;
    const int bRow0 = (wc & 1) * 64;

    // ---- precomputed offsets ----
    // staging: thread covers 16B chunk tid (rows 0-63 of a half) at swizzled source
    const int r0  = tid >> 3;
    const int lc0 = (tid & 7) ^ (r0 & 7);
    const size_t tOff = (size_t)r0 * D_DIM + lc0 * 8;   // elements
    const int ldst = tid * 16;                          // LDS byte slot

    // fragment read bases (bytes into sm); +m*2048 / +8192(hi rows) / +n*2048 are imms
    const int sw0 = (h4 ^ xorv) << 4;          // ks=0 swizzled byte col
    const int sw1 = ((4 + h4) ^ xorv) << 4;    // ks=1
    const int aB0 = wr * SM_HALF + l15 * 128 + sw0;
    const int aB1 = wr * SM_HALF + l15 * 128 + sw1;
    const int bB0 = SM_BOFF + (wc >> 1) * SM_HALF + (bRow0 + l15) * 128 + sw0;
    const int bB1 = SM_BOFF + (wc >> 1) * SM_HALF + (bRow0 + l15) * 128 + sw1;

    auto stage_tile = [&](int kt, char* dst) {
        const u16* Ab = A + (size_t)rowBase * D_DIM + kt * BK;
        const u16* Bb = B + (size_t)colBase * D_DIM + kt * BK;
        GLL(Ab + tOff,                        dst + ldst);
        GLL(Ab + tOff + (size_t)64  * D_DIM,  dst + 8192 + ldst);
        GLL(Ab + tOff + (size_t)128 * D_DIM,  dst + SM_HALF + ldst);
        GLL(Ab + tOff + (size_t)192 * D_DIM,  dst + SM_HALF + 8192 + ldst);
        GLL(Bb + tOff,                        dst + SM_BOFF + ldst);
        GLL(Bb + tOff + (size_t)64  * D_DIM,  dst + SM_BOFF + 8192 + ldst);
        GLL(Bb + tOff + (size_t)128 * D_DIM,  dst + SM_BOFF + SM_HALF + ldst);
        GLL(Bb + tOff + (size_t)192 * D_DIM,  dst + SM_BOFF + SM_HALF + 8192 + ldst);
    };

    // ---- prologue: epilogue tables + tile 0; full drain once ----
    if (tid < 256) {
        ((float*)(sm + SM_F2))[tid] = f2[rowBase + tid];
        ((int*)(sm + SM_LAB))[tid]  = labels[rowBase + tid];
    } else {
        ((float*)(sm + SM_C2))[tid - 256] = c2[colBase + (tid - 256)];
    }
    stage_tile(0, sm);
    __syncthreads();

    v4f acc[8][4];
    #pragma unroll
    for (int m = 0; m < 8; ++m)
        #pragma unroll
        for (int n = 0; n < 4; ++n) acc[m][n] = (v4f){0.f, 0.f, 0.f, 0.f};

    #pragma unroll 2
    for (int kt = 0; kt < KTILES; ++kt) {
        const char* smc = sm + (kt & 1) * SM_BUF;
        char*      bufn = sm + ((kt + 1) & 1) * SM_BUF;

        // stage next tile first: 8 GLL in flight for the whole tile
        if (kt < KTILES - 1) stage_tile(kt + 1, bufn);

        // all 24 fragment reads (ks0 then ks1); MFMAs below let the compiler
        // emit counted lgkmcnt so ks1 LDS service overlaps ks0 MFMA drain
        v8bf a0[8], b0[4], a1[8], b1[4];
        #pragma unroll
        for (int m = 0; m < 4; ++m) {
            a0[m]     = *(const v8bf*)(smc + aB0 + m * 2048);
            a0[m + 4] = *(const v8bf*)(smc + aB0 + m * 2048 + 8192);
            a1[m]     = *(const v8bf*)(smc + aB1 + m * 2048);
            a1[m + 4] = *(const v8bf*)(smc + aB1 + m * 2048 + 8192);
        }
        #pragma unroll
        for (int n = 0; n < 4; ++n) {
            b0[n] = *(const v8bf*)(smc + bB0 + n * 2048);
            b1[n] = *(const v8bf*)(smc + bB1 + n * 2048);
        }

        __builtin_amdgcn_s_setprio(1);
        #pragma unroll
        for (int m = 0; m < 8; ++m)
            #pragma unroll
            for (int n = 0; n < 4; ++n)
                MFMA(acc[m][n], a0[m], b0[n]);
        #pragma unroll
        for (int m = 0; m < 8; ++m)
            #pragma unroll
            for (int n = 0; n < 4; ++n)
                MFMA(acc[m][n], a1[m], b1[n]);
        __builtin_amdgcn_s_setprio(0);

        if (kt < KTILES - 1) {
            asm volatile("s_waitcnt vmcnt(0)" ::: "memory");
            BARRIER();
        }
    }

    // Epilogue: dis = -5*(f2 + c2 - 2*dot); exp; per-row sums; label capture.
    const float* f2s  = (const float*)(sm + SM_F2);
    const float* c2s  = (const float*)(sm + SM_C2);
    const int*   labs = (const int*)(sm + SM_LAB);
    #pragma unroll
    for (int m = 0; m < 8; ++m) {
        float s[4] = {0.f, 0.f, 0.f, 0.f};
        const int lr0 = wr * 128 + m * 16 + h4 * 4;
        #pragma unroll
        for (int n = 0; n < 4; ++n) {
            const int lcol = wc * 64 + n * 16 + l15;
            const int gcol = colBase + lcol;
            const float cc = c2s[lcol];
            #pragma unroll
            for (int j = 0; j < 4; ++j) {
                const int lr = lr0 + j;
                float dis = -5.0f * (f2s[lr] + cc - 2.0f * acc[m][n][j]);
                float e = __expf(dis);
                s[j] += e;
                if (labs[lr] == gcol) posdis[rowBase + lr] = dis;
            }
        }
        #pragma unroll
        for (int msk = 1; msk < 16; msk <<= 1) {
            #pragma unroll
            for (int j = 0; j < 4; ++j) s[j] += __shfl_xor(s[j], msk, 64);
        }
        if (l15 == 0) {
            #pragma unroll
            for (int j = 0; j < 4; ++j)
                atomicAdd(&rowsum[rowBase + lr0 + j], s[j]);
        }
    }
}

// Final scalar reduction: loss and unbiased variance (f64 accumulation).
__global__ __launch_bounds__(256) void finalize_kernel(
    const float* __restrict__ posdis, const float* __restrict__ pose,
    const float* __restrict__ rowsum, const int* __restrict__ labels,
    const float* __restrict__ bias, float* __restrict__ out)
{
    int t = threadIdx.x;
    double sl = 0.0, sp = 0.0, sp2 = 0.0;
    for (int r = t; r < N_ROWS; r += 256) {
        float pd = posdis[r];                 // bf16-path label term (matches rowsum)
        float p  = pose[r] + bias[labels[r]]; // exact-path pos_metric
        float num = __expf(p);
        float den = rowsum[r] - __expf(pd) + num;
        sl  += (double)(logf(den) - p);
        sp  += (double)p;
        sp2 += (double)p * (double)p;
    }
    #pragma unroll
    for (int m = 1; m < 64; m <<= 1) {
        sl  += __shfl_xor(sl,  m, 64);
        sp  += __shfl_xor(sp,  m, 64);
        sp2 += __shfl_xor(sp2, m, 64);
    }
    __shared__ double sh[3][4];
    int w = t >> 6, lane = t & 63;
    if (lane == 0) { sh[0][w] = sl; sh[1][w] = sp; sh[2][w] = sp2; }
    __syncthreads();
    if (t == 0) {
        sl  = sh[0][0] + sh[0][1] + sh[0][2] + sh[0][3];
        sp  = sh[1][0] + sh[1][1] + sh[1][2] + sh[1][3];
        sp2 = sh[2][0] + sh[2][1] + sh[2][2] + sh[2][3];
        const double N = (double)N_ROWS;
        double mean = sp / N;
        double var  = (sp2 - N * mean * mean) / (N - 1.0);
        double loss = sl / N + var;
        out[0] = (float)loss;
        out[1] = (float)var;
    }
}

extern "C" void kernel_launch(void* const* d_in, const int* in_sizes, int n_in,
                              void* d_out, int out_size, void* d_ws, size_t ws_size,
                              hipStream_t stream) {
    const float* features = (const float*)d_in[0];
    const int*   labels   = (const int*)d_in[1];
    const float* centers  = (const float*)d_in[2];
    const float* bias     = (const float*)d_in[3];
    float* out = (float*)d_out;
    char* ws = (char*)d_ws;

    // Workspace layout (16B aligned), ~19.1 MB total.
    u16*   fb     = (u16*)(ws);                 // 8192*512*2  = 8388608
    u16*   cb     = (u16*)(ws + 8388608);       // 10240*512*2 = 10485760
    float* f2     = (float*)(ws + 18874368);    // 8192*4
    float* c2     = (float*)(ws + 18907136);    // 10240*4
    float* rowsum = (float*)(ws + 18948096);    // 8192*4
    float* posdis = (float*)(ws + 18980864);    // 8192*4
    float* pose   = (float*)(ws + 19013632);    // 8192*4

    hipMemsetAsync(rowsum, 0, N_ROWS * sizeof(float), stream);

    hipLaunchKernelGGL(norm_rows_kernel, dim3(N_ROWS / 4), dim3(256), 0, stream,
                       features, fb, f2, N_ROWS, N_ROWS);
    hipLaunchKernelGGL(norm_rows_kernel, dim3(C_PAD / 4), dim3(256), 0, stream,
                       centers, cb, c2, C_REAL, C_PAD);
    hipLaunchKernelGGL(pos_exact_kernel, dim3(N_ROWS / 4), dim3(256), 0, stream,
                       features, centers, labels, pose);

    hipFuncSetAttribute(reinterpret_cast<const void*>(gemm_kernel),
                        hipFuncAttributeMaxDynamicSharedMemorySize, SM_TOTAL);
    hipLaunchKernelGGL(gemm_kernel, dim3(C_PAD / BN, N_ROWS / BM), dim3(512), SM_TOTAL, stream,
                       fb, cb, f2, c2, labels, rowsum, posdis);

    hipLaunchKernelGGL(finalize_kernel, dim3(1), dim3(256), 0, stream,
                       posdis, pose, rowsum, labels, bias, out);
}

// Round 5
// 229.397 us; speedup vs baseline: 1.2294x; 1.1817x over previous
//
#include <hip/hip_runtime.h>
#include <hip/hip_bf16.h>
#include <stdint.h>

typedef unsigned short u16;
typedef __bf16 v8bf __attribute__((ext_vector_type(8)));
typedef float  v4f  __attribute__((ext_vector_type(4)));

#define N_ROWS 8192
#define C_REAL 10000
#define C_PAD  10240   /* 40 * 256 */
#define D_DIM  512
#define BM 256
#define BN 256
#define BK2 32
#define NSTEP (D_DIM / BK2)   /* 16 */

/* LDS map (bytes): 4 ring slots of 32KB (A 16KB @0, B 16KB @16384 within slot),
   then f2s @131072, c2s @132096, labs @133120. */
#define SLOT    32768
#define SM_BOFF 16384
#define SM_F2  131072
#define SM_C2  132096
#define SM_LAB 133120
#define SM_TOTAL 134144
static_assert(SM_TOTAL <= 160 * 1024, "LDS budget");

#define BARRIER() do { asm volatile("" ::: "memory"); \
                       __builtin_amdgcn_s_barrier();  \
                       asm volatile("" ::: "memory"); } while (0)
#define MFMA(d, a, b) d = __builtin_amdgcn_mfma_f32_16x16x32_bf16(a, b, d, 0, 0, 0)
#define GLL(gp, lp) __builtin_amdgcn_global_load_lds( \
    (const __attribute__((address_space(1))) void*)(gp), \
    (__attribute__((address_space(3))) void*)(lp), 16, 0, 0)

__device__ __forceinline__ unsigned pack2bf(float a, float b) {
    unsigned short ua = __builtin_bit_cast(unsigned short, (__bf16)a);
    unsigned short ub = __builtin_bit_cast(unsigned short, (__bf16)b);
    return (unsigned)ua | ((unsigned)ub << 16);
}

// One wave per row: L2-normalize, write bf16 row + f32 sum-of-squares-of-normalized.
// Rows >= nreal are padding: bf16 zeros, o2 = 1e30 (=> dis = -5e30 => exp = 0).
__global__ __launch_bounds__(256) void norm_rows_kernel(
    const float* __restrict__ x, u16* __restrict__ ob, float* __restrict__ o2,
    int nreal, int ntotal)
{
    int row  = blockIdx.x * 4 + (threadIdx.x >> 6);
    int lane = threadIdx.x & 63;
    if (row >= ntotal) return;
    uint2* orow = (uint2*)(ob + (size_t)row * D_DIM);
    if (row >= nreal) {
        uint2 z; z.x = 0u; z.y = 0u;
        orow[lane] = z; orow[64 + lane] = z;
        if (lane == 0) o2[row] = 1e30f;
        return;
    }
    const float4* xr = (const float4*)(x + (size_t)row * D_DIM);
    float4 v0 = xr[lane];
    float4 v1 = xr[64 + lane];
    float s = v0.x*v0.x + v0.y*v0.y + v0.z*v0.z + v0.w*v0.w
            + v1.x*v1.x + v1.y*v1.y + v1.z*v1.z + v1.w*v1.w;
    #pragma unroll
    for (int m = 1; m < 64; m <<= 1) s += __shfl_xor(s, m, 64);
    float nrm = sqrtf(s);
    float inv = 1.0f / fmaxf(nrm, 1e-12f);
    if (lane == 0) o2[row] = s * inv * inv;
    uint2 p0, p1;
    p0.x = pack2bf(v0.x * inv, v0.y * inv);
    p0.y = pack2bf(v0.z * inv, v0.w * inv);
    p1.x = pack2bf(v1.x * inv, v1.y * inv);
    p1.y = pack2bf(v1.z * inv, v1.w * inv);
    orow[lane]      = p0;
    orow[64 + lane] = p1;
}

// Exact (f32) positive-class distance: one wave per row, gathered center row.
__global__ __launch_bounds__(256) void pos_exact_kernel(
    const float* __restrict__ feat, const float* __restrict__ cent,
    const int* __restrict__ labels, float* __restrict__ pose)
{
    int row  = blockIdx.x * 4 + (threadIdx.x >> 6);
    int lane = threadIdx.x & 63;
    int lab  = labels[row];
    const float4* fr = (const float4*)(feat + (size_t)row * D_DIM);
    const float4* cr = (const float4*)(cent + (size_t)lab * D_DIM);
    float sf = 0.f, sc = 0.f, sd = 0.f;
    #pragma unroll
    for (int i = 0; i < 2; ++i) {
        float4 a = fr[i * 64 + lane];
        float4 b = cr[i * 64 + lane];
        sf += a.x*a.x + a.y*a.y + a.z*a.z + a.w*a.w;
        sc += b.x*b.x + b.y*b.y + b.z*b.z + b.w*b.w;
        sd += a.x*b.x + a.y*b.y + a.z*b.z + a.w*b.w;
    }
    #pragma unroll
    for (int m = 1; m < 64; m <<= 1) {
        sf += __shfl_xor(sf, m, 64);
        sc += __shfl_xor(sc, m, 64);
        sd += __shfl_xor(sd, m, 64);
    }
    if (lane == 0) {
        float nf = fmaxf(sqrtf(sf), 1e-12f);
        float nc = fmaxf(sqrtf(sc), 1e-12f);
        float invf = 1.f / nf, invc = 1.f / nc;
        float f2n = sf * invf * invf;
        float c2n = sc * invc * invc;
        float dtn = sd * invf * invc;
        pose[row] = -5.0f * (f2n + c2n - 2.0f * dtn);
    }
}

// 256x256 8-wave MFMA GEMM, BK=32 with 4-slot LDS ring staged 2 steps ahead:
// steady-state wait is vmcnt(4) (never a full drain until the tail), one
// barrier per K-step. Linear LDS layout (64B row stride is inherently
// bank-balanced at BK=32 for both gll writes and b128 frag reads).
// Grid (40,32): linear id = x + 40*y, 40%8==0 => XCD = x%8 => each XCD sees
// 5 col-tiles + ~6 row-tiles, all L2-resident (round-2 measured FETCH 38MB).
__global__ __launch_bounds__(512, 2) void gemm_kernel(
    const u16* __restrict__ A, const u16* __restrict__ B,
    const float* __restrict__ f2, const float* __restrict__ c2,
    const int* __restrict__ labels,
    float* __restrict__ rowsum, float* __restrict__ posdis)
{
    extern __shared__ char sm[];
    const int rowBase = blockIdx.y * BM;
    const int colBase = blockIdx.x * BN;
    const int tid  = threadIdx.x;
    const int lane = tid & 63;
    const int w    = tid >> 6;
    const int wr   = w >> 2;        // 0..1 : 128-row group
    const int wc   = w & 3;         // 0..3 : 64-col group
    const int l15  = lane & 15;
    const int h4   = lane >> 4;

    // ---- staging (linear): A/B tile = 256 rows x 32 cols = 1024 x 16B chunks;
    // thread covers chunk ids {tid, tid+512} for A and for B.
    const size_t g0 = (size_t)(tid >> 2) * D_DIM + (tid & 3) * 8;
    const size_t g1 = (size_t)((tid + 512) >> 2) * D_DIM + ((tid + 512) & 3) * 8;
    const int d0 = tid * 16, d1 = (tid + 512) * 16;
    const u16* Abase = A + (size_t)rowBase * D_DIM;
    const u16* Bbase = B + (size_t)colBase * D_DIM;

    auto stage = [&](int k) {
        char* dst = sm + (k & 3) * SLOT;
        const u16* Ak = Abase + k * BK2;
        const u16* Bk = Bbase + k * BK2;
        GLL(Ak + g0, dst + d0);
        GLL(Ak + g1, dst + d1);
        GLL(Bk + g0, dst + SM_BOFF + d0);
        GLL(Bk + g1, dst + SM_BOFF + d1);
    };

    // ---- fragment read offsets (bytes within a slot); +m*1024 / +n*1024 imms
    const int aBoff = wr * 8192 + l15 * 64 + h4 * 16;
    const int bBoff = SM_BOFF + wc * 4096 + l15 * 64 + h4 * 16;

    // ---- prologue: tables + stage steps 0,1; wait step-0 batch only ----
    if (tid < 256) {
        ((float*)(sm + SM_F2))[tid] = f2[rowBase + tid];
        ((int*)(sm + SM_LAB))[tid]  = labels[rowBase + tid];
    } else {
        ((float*)(sm + SM_C2))[tid - 256] = c2[colBase + (tid - 256)];
    }
    stage(0);
    stage(1);
    asm volatile("s_waitcnt vmcnt(4) lgkmcnt(0)" ::: "memory");
    __builtin_amdgcn_s_barrier();

    v4f acc[8][4];
    #pragma unroll
    for (int m = 0; m < 8; ++m)
        #pragma unroll
        for (int n = 0; n < 4; ++n) acc[m][n] = (v4f){0.f, 0.f, 0.f, 0.f};

    #pragma unroll 4
    for (int k = 0; k < NSTEP; ++k) {
        const char* smc = sm + (k & 3) * SLOT;
        if (k + 2 < NSTEP) stage(k + 2);

        v8bf a[8], b[4];
        #pragma unroll
        for (int m = 0; m < 8; ++m) a[m] = *(const v8bf*)(smc + aBoff + m * 1024);
        #pragma unroll
        for (int n = 0; n < 4; ++n) b[n] = *(const v8bf*)(smc + bBoff + n * 1024);

        __builtin_amdgcn_s_setprio(1);
        #pragma unroll
        for (int m = 0; m < 8; ++m)
            #pragma unroll
            for (int n = 0; n < 4; ++n)
                MFMA(acc[m][n], a[m], b[n]);
        __builtin_amdgcn_s_setprio(0);

        if (k + 3 < NSTEP)       asm volatile("s_waitcnt vmcnt(4)" ::: "memory");
        else if (k + 2 == NSTEP) asm volatile("s_waitcnt vmcnt(0)" ::: "memory");
        if (k + 1 < NSTEP) BARRIER();
    }

    // Epilogue: dis = -5*(f2 + c2 - 2*dot); exp; per-row sums; label capture.
    const float* f2s  = (const float*)(sm + SM_F2);
    const float* c2s  = (const float*)(sm + SM_C2);
    const int*   labs = (const int*)(sm + SM_LAB);
    #pragma unroll
    for (int m = 0; m < 8; ++m) {
        float s[4] = {0.f, 0.f, 0.f, 0.f};
        const int lr0 = wr * 128 + m * 16 + h4 * 4;
        #pragma unroll
        for (int n = 0; n < 4; ++n) {
            const int lcol = wc * 64 + n * 16 + l15;
            const int gcol = colBase + lcol;
            const float cc = c2s[lcol];
            #pragma unroll
            for (int j = 0; j < 4; ++j) {
                const int lr = lr0 + j;
                float dis = -5.0f * (f2s[lr] + cc - 2.0f * acc[m][n][j]);
                float e = __expf(dis);
                s[j] += e;
                if (labs[lr] == gcol) posdis[rowBase + lr] = dis;
            }
        }
        #pragma unroll
        for (int msk = 1; msk < 16; msk <<= 1) {
            #pragma unroll
            for (int j = 0; j < 4; ++j) s[j] += __shfl_xor(s[j], msk, 64);
        }
        if (l15 == 0) {
            #pragma unroll
            for (int j = 0; j < 4; ++j)
                atomicAdd(&rowsum[rowBase + lr0 + j], s[j]);
        }
    }
}

// Final scalar reduction: loss and unbiased variance (f64 accumulation).
__global__ __launch_bounds__(256) void finalize_kernel(
    const float* __restrict__ posdis, const float* __restrict__ pose,
    const float* __restrict__ rowsum, const int* __restrict__ labels,
    const float* __restrict__ bias, float* __restrict__ out)
{
    int t = threadIdx.x;
    double sl = 0.0, sp = 0.0, sp2 = 0.0;
    for (int r = t; r < N_ROWS; r += 256) {
        float pd = posdis[r];                 // bf16-path label term (matches rowsum)
        float p  = pose[r] + bias[labels[r]]; // exact-path pos_metric
        float num = __expf(p);
        float den = rowsum[r] - __expf(pd) + num;
        sl  += (double)(logf(den) - p);
        sp  += (double)p;
        sp2 += (double)p * (double)p;
    }
    #pragma unroll
    for (int m = 1; m < 64; m <<= 1) {
        sl  += __shfl_xor(sl,  m, 64);
        sp  += __shfl_xor(sp,  m, 64);
        sp2 += __shfl_xor(sp2, m, 64);
    }
    __shared__ double sh[3][4];
    int w = t >> 6, lane = t & 63;
    if (lane == 0) { sh[0][w] = sl; sh[1][w] = sp; sh[2][w] = sp2; }
    __syncthreads();
    if (t == 0) {
        sl  = sh[0][0] + sh[0][1] + sh[0][2] + sh[0][3];
        sp  = sh[1][0] + sh[1][1] + sh[1][2] + sh[1][3];
        sp2 = sh[2][0] + sh[2][1] + sh[2][2] + sh[2][3];
        const double N = (double)N_ROWS;
        double mean = sp / N;
        double var  = (sp2 - N * mean * mean) / (N - 1.0);
        double loss = sl / N + var;
        out[0] = (float)loss;
        out[1] = (float)var;
    }
}

extern "C" void kernel_launch(void* const* d_in, const int* in_sizes, int n_in,
                              void* d_out, int out_size, void* d_ws, size_t ws_size,
                              hipStream_t stream) {
    const float* features = (const float*)d_in[0];
    const int*   labels   = (const int*)d_in[1];
    const float* centers  = (const float*)d_in[2];
    const float* bias     = (const float*)d_in[3];
    float* out = (float*)d_out;
    char* ws = (char*)d_ws;

    // Workspace layout (16B aligned), ~19.1 MB total.
    u16*   fb     = (u16*)(ws);                 // 8192*512*2  = 8388608
    u16*   cb     = (u16*)(ws + 8388608);       // 10240*512*2 = 10485760
    float* f2     = (float*)(ws + 18874368);    // 8192*4
    float* c2     = (float*)(ws + 18907136);    // 10240*4
    float* rowsum = (float*)(ws + 18948096);    // 8192*4
    float* posdis = (float*)(ws + 18980864);    // 8192*4
    float* pose   = (float*)(ws + 19013632);    // 8192*4

    hipMemsetAsync(rowsum, 0, N_ROWS * sizeof(float), stream);

    hipLaunchKernelGGL(norm_rows_kernel, dim3(N_ROWS / 4), dim3(256), 0, stream,
                       features, fb, f2, N_ROWS, N_ROWS);
    hipLaunchKernelGGL(norm_rows_kernel, dim3(C_PAD / 4), dim3(256), 0, stream,
                       centers, cb, c2, C_REAL, C_PAD);
    hipLaunchKernelGGL(pos_exact_kernel, dim3(N_ROWS / 4), dim3(256), 0, stream,
                       features, centers, labels, pose);

    hipFuncSetAttribute(reinterpret_cast<const void*>(gemm_kernel),
                        hipFuncAttributeMaxDynamicSharedMemorySize, SM_TOTAL);
    hipLaunchKernelGGL(gemm_kernel, dim3(C_PAD / BN, N_ROWS / BM), dim3(512), SM_TOTAL, stream,
                       fb, cb, f2, c2, labels, rowsum, posdis);

    hipLaunchKernelGGL(finalize_kernel, dim3(1), dim3(256), 0, stream,
                       posdis, pose, rowsum, labels, bias, out);
}

// Round 6
// 210.252 us; speedup vs baseline: 1.3413x; 1.0911x over previous
//
#include <hip/hip_runtime.h>
#include <hip/hip_bf16.h>
#include <stdint.h>

typedef unsigned short u16;
typedef __bf16 v8bf __attribute__((ext_vector_type(8)));
typedef float  v4f  __attribute__((ext_vector_type(4)));

#define N_ROWS 8192
#define C_REAL 10000
#define C_PAD  10240   /* 40 * 256 */
#define D_DIM  512
#define BM 256
#define BN 256
#define BK 64
#define KTILES (D_DIM / BK)   /* 8 */

/* LDS map (bytes): 2 slots of 64KB (A 32KB @0 = 256 rows x 128B swizzled,
   B 32KB @32768), then f2s @131072, c2s @132096, labs @133120. */
#define SM_SLOT  65536
#define SM_BOFF  32768
#define SM_F2   131072
#define SM_C2   132096
#define SM_LAB  133120
#define SM_TOTAL 134144
static_assert(SM_TOTAL <= 160 * 1024, "LDS budget");

#define BARRIER() do { asm volatile("" ::: "memory"); \
                       __builtin_amdgcn_s_barrier();  \
                       asm volatile("" ::: "memory"); } while (0)
#define MFMA(d, a, b) d = __builtin_amdgcn_mfma_f32_16x16x32_bf16(a, b, d, 0, 0, 0)
#define GLL(gp, lp) __builtin_amdgcn_global_load_lds( \
    (const __attribute__((address_space(1))) void*)(gp), \
    (__attribute__((address_space(3))) void*)(lp), 16, 0, 0)

__device__ __forceinline__ unsigned pack2bf(float a, float b) {
    unsigned short ua = __builtin_bit_cast(unsigned short, (__bf16)a);
    unsigned short ub = __builtin_bit_cast(unsigned short, (__bf16)b);
    return (unsigned)ua | ((unsigned)ub << 16);
}

// One wave per row: L2-normalize, write bf16 row + f32 sum-of-squares-of-normalized.
// Rows >= nreal are padding: bf16 zeros, o2 = 1e30 (=> dis = -5e30 => exp = 0).
__global__ __launch_bounds__(256) void norm_rows_kernel(
    const float* __restrict__ x, u16* __restrict__ ob, float* __restrict__ o2,
    int nreal, int ntotal)
{
    int row  = blockIdx.x * 4 + (threadIdx.x >> 6);
    int lane = threadIdx.x & 63;
    if (row >= ntotal) return;
    uint2* orow = (uint2*)(ob + (size_t)row * D_DIM);
    if (row >= nreal) {
        uint2 z; z.x = 0u; z.y = 0u;
        orow[lane] = z; orow[64 + lane] = z;
        if (lane == 0) o2[row] = 1e30f;
        return;
    }
    const float4* xr = (const float4*)(x + (size_t)row * D_DIM);
    float4 v0 = xr[lane];
    float4 v1 = xr[64 + lane];
    float s = v0.x*v0.x + v0.y*v0.y + v0.z*v0.z + v0.w*v0.w
            + v1.x*v1.x + v1.y*v1.y + v1.z*v1.z + v1.w*v1.w;
    #pragma unroll
    for (int m = 1; m < 64; m <<= 1) s += __shfl_xor(s, m, 64);
    float nrm = sqrtf(s);
    float inv = 1.0f / fmaxf(nrm, 1e-12f);
    if (lane == 0) o2[row] = s * inv * inv;
    uint2 p0, p1;
    p0.x = pack2bf(v0.x * inv, v0.y * inv);
    p0.y = pack2bf(v0.z * inv, v0.w * inv);
    p1.x = pack2bf(v1.x * inv, v1.y * inv);
    p1.y = pack2bf(v1.z * inv, v1.w * inv);
    orow[lane]      = p0;
    orow[64 + lane] = p1;
}

// Exact (f32) positive-class distance: one wave per row, gathered center row.
__global__ __launch_bounds__(256) void pos_exact_kernel(
    const float* __restrict__ feat, const float* __restrict__ cent,
    const int* __restrict__ labels, float* __restrict__ pose)
{
    int row  = blockIdx.x * 4 + (threadIdx.x >> 6);
    int lane = threadIdx.x & 63;
    int lab  = labels[row];
    const float4* fr = (const float4*)(feat + (size_t)row * D_DIM);
    const float4* cr = (const float4*)(cent + (size_t)lab * D_DIM);
    float sf = 0.f, sc = 0.f, sd = 0.f;
    #pragma unroll
    for (int i = 0; i < 2; ++i) {
        float4 a = fr[i * 64 + lane];
        float4 b = cr[i * 64 + lane];
        sf += a.x*a.x + a.y*a.y + a.z*a.z + a.w*a.w;
        sc += b.x*b.x + b.y*b.y + b.z*b.z + b.w*b.w;
        sd += a.x*b.x + a.y*b.y + a.z*b.z + a.w*b.w;
    }
    #pragma unroll
    for (int m = 1; m < 64; m <<= 1) {
        sf += __shfl_xor(sf, m, 64);
        sc += __shfl_xor(sc, m, 64);
        sd += __shfl_xor(sd, m, 64);
    }
    if (lane == 0) {
        float nf = fmaxf(sqrtf(sf), 1e-12f);
        float nc = fmaxf(sqrtf(sc), 1e-12f);
        float invf = 1.f / nf, invc = 1.f / nc;
        float f2n = sf * invf * invf;
        float c2n = sc * invc * invc;
        float dtn = sd * invf * invc;
        pose[row] = -5.0f * (f2n + c2n - 2.0f * dtn);
    }
}

// 256x256x(BK=64) 8-wave MFMA GEMM, 2-slot double buffer:
//  - XOR-8 swizzled LDS (round-2 layout, measured 0 bank conflicts);
//  - stage tile k+1 at the TOP of tile k => vmcnt(0) at tile end has a full
//    tile (~2000+ cyc) of slack, so it never stalls hot;
//  - ONE barrier per tile; fragment reads split ks0/ks1 (<=12 live frags,
//    no round-4 spills); all LDS offsets precomputed.
// Grid (40,32): linear id = x + 40*y, 40%8==0 => XCD = x%8 => each XCD sees
// 5 col-tiles + ~6 row-tiles, all L2-resident (round-2 measured FETCH 38MB).
__global__ __launch_bounds__(512, 2) void gemm_kernel(
    const u16* __restrict__ A, const u16* __restrict__ B,
    const float* __restrict__ f2, const float* __restrict__ c2,
    const int* __restrict__ labels,
    float* __restrict__ rowsum, float* __restrict__ posdis)
{
    extern __shared__ char sm[];
    const int rowBase = blockIdx.y * BM;
    const int colBase = blockIdx.x * BN;
    const int tid  = threadIdx.x;
    const int lane = tid & 63;
    const int w    = tid >> 6;
    const int wr   = w >> 2;        // 0..1 : 128-row group
    const int wc   = w & 3;         // 0..3 : 64-col group
    const int l15  = lane & 15;
    const int h4   = lane >> 4;

    // ---- staging offsets: chunk id c = tid + i*512 (i=0..3), r = c>>3,
    // pc = c&7, logical chunk lc = pc ^ (r&7). Since i*512 keeps (c&7) and
    // (r&7) fixed, gOff/lds-slot are the same formula for all i.
    const int r0  = tid >> 3;
    const int lc0 = (tid & 7) ^ (r0 & 7);
    const size_t gOff = (size_t)r0 * D_DIM + lc0 * 8;   // elements
    const int d0 = tid * 16;                            // LDS byte slot (i=0)
    const u16* Abase = A + (size_t)rowBase * D_DIM;
    const u16* Bbase = B + (size_t)colBase * D_DIM;

    auto stage = [&](int k, char* dst) {
        const u16* Ak = Abase + k * BK + gOff;   // +i*64 rows = +32768 elems
        const u16* Bk = Bbase + k * BK + gOff;
        GLL(Ak,          dst + d0);
        GLL(Ak + 32768,  dst + d0 + 8192);
        GLL(Ak + 65536,  dst + d0 + 16384);
        GLL(Ak + 98304,  dst + d0 + 24576);
        GLL(Bk,          dst + SM_BOFF + d0);
        GLL(Bk + 32768,  dst + SM_BOFF + d0 + 8192);
        GLL(Bk + 65536,  dst + SM_BOFF + d0 + 16384);
        GLL(Bk + 98304,  dst + SM_BOFF + d0 + 24576);
    };

    // ---- fragment read bases (bytes); row = wr*128+m*16+l15 (A) has
    // row&7 == l15&7, so the swizzled column is ((ks*4+h4) ^ (l15&7)).
    const int s0 = ((h4)     ^ (l15 & 7)) << 4;   // ks=0
    const int s1 = ((4 + h4) ^ (l15 & 7)) << 4;   // ks=1
    const int aB0 = wr * 16384 + l15 * 128 + s0;
    const int aB1 = wr * 16384 + l15 * 128 + s1;
    const int bB0 = SM_BOFF + wc * 8192 + l15 * 128 + s0;
    const int bB1 = SM_BOFF + wc * 8192 + l15 * 128 + s1;

    // ---- prologue: epilogue tables + tile 0; full drain once ----
    if (tid < 256) {
        ((float*)(sm + SM_F2))[tid] = f2[rowBase + tid];
        ((int*)(sm + SM_LAB))[tid]  = labels[rowBase + tid];
    } else {
        ((float*)(sm + SM_C2))[tid - 256] = c2[colBase + (tid - 256)];
    }
    stage(0, sm);
    __syncthreads();

    v4f acc[8][4];
    #pragma unroll
    for (int m = 0; m < 8; ++m)
        #pragma unroll
        for (int n = 0; n < 4; ++n) acc[m][n] = (v4f){0.f, 0.f, 0.f, 0.f};

    #pragma unroll 2
    for (int k = 0; k < KTILES; ++k) {
        const char* smc = sm + (k & 1) * SM_SLOT;
        char*      bufn = sm + ((k + 1) & 1) * SM_SLOT;

        // stage next tile first: 8 GLL get a full tile of latency slack
        if (k + 1 < KTILES) stage(k + 1, bufn);

        v8bf a[8], b[4];
        // ---- ks = 0 ----
        #pragma unroll
        for (int m = 0; m < 8; ++m) a[m] = *(const v8bf*)(smc + aB0 + m * 2048);
        #pragma unroll
        for (int n = 0; n < 4; ++n) b[n] = *(const v8bf*)(smc + bB0 + n * 2048);
        __builtin_amdgcn_s_setprio(1);
        #pragma unroll
        for (int m = 0; m < 8; ++m)
            #pragma unroll
            for (int n = 0; n < 4; ++n)
                MFMA(acc[m][n], a[m], b[n]);
        __builtin_amdgcn_s_setprio(0);
        // ---- ks = 1 (reuse a/b regs) ----
        #pragma unroll
        for (int m = 0; m < 8; ++m) a[m] = *(const v8bf*)(smc + aB1 + m * 2048);
        #pragma unroll
        for (int n = 0; n < 4; ++n) b[n] = *(const v8bf*)(smc + bB1 + n * 2048);
        __builtin_amdgcn_s_setprio(1);
        #pragma unroll
        for (int m = 0; m < 8; ++m)
            #pragma unroll
            for (int n = 0; n < 4; ++n)
                MFMA(acc[m][n], a[m], b[n]);
        __builtin_amdgcn_s_setprio(0);

        if (k + 1 < KTILES) {
            asm volatile("s_waitcnt vmcnt(0)" ::: "memory");
            BARRIER();
        }
    }

    // Epilogue: dis = -5*(f2 + c2 - 2*dot); exp; per-row sums; label capture.
    const float* f2s  = (const float*)(sm + SM_F2);
    const float* c2s  = (const float*)(sm + SM_C2);
    const int*   labs = (const int*)(sm + SM_LAB);
    #pragma unroll
    for (int m = 0; m < 8; ++m) {
        float s[4] = {0.f, 0.f, 0.f, 0.f};
        const int lr0 = wr * 128 + m * 16 + h4 * 4;
        #pragma unroll
        for (int n = 0; n < 4; ++n) {
            const int lcol = wc * 64 + n * 16 + l15;
            const int gcol = colBase + lcol;
            const float cc = c2s[lcol];
            #pragma unroll
            for (int j = 0; j < 4; ++j) {
                const int lr = lr0 + j;
                float dis = -5.0f * (f2s[lr] + cc - 2.0f * acc[m][n][j]);
                float e = __expf(dis);
                s[j] += e;
                if (labs[lr] == gcol) posdis[rowBase + lr] = dis;
            }
        }
        #pragma unroll
        for (int msk = 1; msk < 16; msk <<= 1) {
            #pragma unroll
            for (int j = 0; j < 4; ++j) s[j] += __shfl_xor(s[j], msk, 64);
        }
        if (l15 == 0) {
            #pragma unroll
            for (int j = 0; j < 4; ++j)
                atomicAdd(&rowsum[rowBase + lr0 + j], s[j]);
        }
    }
}

// Final scalar reduction: loss and unbiased variance (f64 accumulation).
__global__ __launch_bounds__(256) void finalize_kernel(
    const float* __restrict__ posdis, const float* __restrict__ pose,
    const float* __restrict__ rowsum, const int* __restrict__ labels,
    const float* __restrict__ bias, float* __restrict__ out)
{
    int t = threadIdx.x;
    double sl = 0.0, sp = 0.0, sp2 = 0.0;
    for (int r = t; r < N_ROWS; r += 256) {
        float pd = posdis[r];                 // bf16-path label term (matches rowsum)
        float p  = pose[r] + bias[labels[r]]; // exact-path pos_metric
        float num = __expf(p);
        float den = rowsum[r] - __expf(pd) + num;
        sl  += (double)(logf(den) - p);
        sp  += (double)p;
        sp2 += (double)p * (double)p;
    }
    #pragma unroll
    for (int m = 1; m < 64; m <<= 1) {
        sl  += __shfl_xor(sl,  m, 64);
        sp  += __shfl_xor(sp,  m, 64);
        sp2 += __shfl_xor(sp2, m, 64);
    }
    __shared__ double sh[3][4];
    int w = t >> 6, lane = t & 63;
    if (lane == 0) { sh[0][w] = sl; sh[1][w] = sp; sh[2][w] = sp2; }
    __syncthreads();
    if (t == 0) {
        sl  = sh[0][0] + sh[0][1] + sh[0][2] + sh[0][3];
        sp  = sh[1][0] + sh[1][1] + sh[1][2] + sh[1][3];
        sp2 = sh[2][0] + sh[2][1] + sh[2][2] + sh[2][3];
        const double N = (double)N_ROWS;
        double mean = sp / N;
        double var  = (sp2 - N * mean * mean) / (N - 1.0);
        double loss = sl / N + var;
        out[0] = (float)loss;
        out[1] = (float)var;
    }
}

extern "C" void kernel_launch(void* const* d_in, const int* in_sizes, int n_in,
                              void* d_out, int out_size, void* d_ws, size_t ws_size,
                              hipStream_t stream) {
    const float* features = (const float*)d_in[0];
    const int*   labels   = (const int*)d_in[1];
    const float* centers  = (const float*)d_in[2];
    const float* bias     = (const float*)d_in[3];
    float* out = (float*)d_out;
    char* ws = (char*)d_ws;

    // Workspace layout (16B aligned), ~19.1 MB total.
    u16*   fb     = (u16*)(ws);                 // 8192*512*2  = 8388608
    u16*   cb     = (u16*)(ws + 8388608);       // 10240*512*2 = 10485760
    float* f2     = (float*)(ws + 18874368);    // 8192*4
    float* c2     = (float*)(ws + 18907136);    // 10240*4
    float* rowsum = (float*)(ws + 18948096);    // 8192*4
    float* posdis = (float*)(ws + 18980864);    // 8192*4
    float* pose   = (float*)(ws + 19013632);    // 8192*4

    hipMemsetAsync(rowsum, 0, N_ROWS * sizeof(float), stream);

    hipLaunchKernelGGL(norm_rows_kernel, dim3(N_ROWS / 4), dim3(256), 0, stream,
                       features, fb, f2, N_ROWS, N_ROWS);
    hipLaunchKernelGGL(norm_rows_kernel, dim3(C_PAD / 4), dim3(256), 0, stream,
                       centers, cb, c2, C_REAL, C_PAD);
    hipLaunchKernelGGL(pos_exact_kernel, dim3(N_ROWS / 4), dim3(256), 0, stream,
                       features, centers, labels, pose);

    hipFuncSetAttribute(reinterpret_cast<const void*>(gemm_kernel),
                        hipFuncAttributeMaxDynamicSharedMemorySize, SM_TOTAL);
    hipLaunchKernelGGL(gemm_kernel, dim3(C_PAD / BN, N_ROWS / BM), dim3(512), SM_TOTAL, stream,
                       fb, cb, f2, c2, labels, rowsum, posdis);

    hipLaunchKernelGGL(finalize_kernel, dim3(1), dim3(256), 0, stream,
                       posdis, pose, rowsum, labels, bias, out);
}